// Round 2
// baseline (3274.411 us; speedup 1.0000x reference)
//
#include <hip/hip_runtime.h>

// B=16,S=1024,E=1024,F=4096,H=16,D=64. N = B*S = 16384 tokens.
// Pipeline: LN1 -> QKV gemm(bf16 MFMA)+bias -> flash attn(fp32) -> proj gemm+bias+resid -> d_out
//           -> LN2 -> [2 row-chunks] lin1 gemm+bias+GELU -> lin2 gemm+bias+resid(in-place d_out)
//
// Compact workspace plan (peak 159,383,552 B ~ 152 MB) — round-1 crash was almost
// certainly a d_ws overflow (408 MB plan), so regions are reused sequentially:
//   0          wqkv_b  bf16 3072x1024   (6 MB)
//   6291456    wo_b    bf16 1024x1024   (2 MB)
//   8388608    w1_b    bf16 4096x1024   (8 MB)
//   16777216   w2_b    bf16 1024x4096   (8 MB)
//   25165824   region1 (32 MB): xn_b -> ctx_b -> xn2_b   (each dead before next writer)
//   58720256   region2 (96 MB): qkv_b -> h chunk (64 MB, FFN split into 2 row-chunks)
// x1 (fp32 16384x1024) lives in d_out; lin2 updates d_out in place (same-thread R->W).

typedef __attribute__((ext_vector_type(8))) short bf16x8;
typedef __attribute__((ext_vector_type(4))) float f32x4;
typedef __attribute__((ext_vector_type(8))) unsigned short u16x8;
typedef __attribute__((ext_vector_type(4))) unsigned short u16x4;

__device__ __forceinline__ float bf2f(unsigned short u) {
    return __uint_as_float(((unsigned int)u) << 16);
}
__device__ __forceinline__ unsigned short f2bf(float f) {
    unsigned int u = __float_as_uint(f);
    u += 0x7fffu + ((u >> 16) & 1u);   // RNE
    return (unsigned short)(u >> 16);
}

// ---------------- fp32 -> bf16 weight conversion ----------------
__global__ __launch_bounds__(256) void cvt_kernel(const float* __restrict__ in,
                                                  unsigned short* __restrict__ out, int n4) {
    int i = blockIdx.x * 256 + threadIdx.x;
    if (i >= n4) return;
    float4 v = ((const float4*)in)[i];
    u16x4 o;
    o[0] = f2bf(v.x); o[1] = f2bf(v.y); o[2] = f2bf(v.z); o[3] = f2bf(v.w);
    ((u16x4*)out)[i] = o;
}

// ---------------- LayerNorm (E=1024), fp32 in -> bf16 out ----------------
__global__ __launch_bounds__(256) void ln_kernel(const float* __restrict__ x,
                                                 const float* __restrict__ w,
                                                 const float* __restrict__ b,
                                                 unsigned short* __restrict__ out) {
    const int row = blockIdx.x;
    const int t = threadIdx.x;
    const float* xr = x + (size_t)row * 1024;
    float4 v = *(const float4*)(xr + t * 4);
    float s = v.x + v.y + v.z + v.w;
    float sq = v.x * v.x + v.y * v.y + v.z * v.z + v.w * v.w;
#pragma unroll
    for (int off = 32; off > 0; off >>= 1) {
        s += __shfl_xor(s, off);
        sq += __shfl_xor(sq, off);
    }
    __shared__ float rs_[4], rq_[4];
    if ((t & 63) == 0) { rs_[t >> 6] = s; rq_[t >> 6] = sq; }
    __syncthreads();
    s = rs_[0] + rs_[1] + rs_[2] + rs_[3];
    sq = rq_[0] + rq_[1] + rq_[2] + rq_[3];
    const float mu = s * (1.0f / 1024.0f);
    const float var = sq * (1.0f / 1024.0f) - mu * mu;
    const float rstd = rsqrtf(var + 1e-5f);
    const int c = t * 4;
    float4 wv = *(const float4*)(w + c);
    float4 bv = *(const float4*)(b + c);
    u16x4 o;
    o[0] = f2bf((v.x - mu) * rstd * wv.x + bv.x);
    o[1] = f2bf((v.y - mu) * rstd * wv.y + bv.y);
    o[2] = f2bf((v.z - mu) * rstd * wv.z + bv.z);
    o[3] = f2bf((v.w - mu) * rstd * wv.w + bv.w);
    *(u16x4*)(out + (size_t)row * 1024 + c) = o;
}

// ---------------- bf16 MFMA GEMM: C[M,N] = A[M,K] @ Bt[N,K]^T + epilogue ----------------
// 128x128 tile, BK=32, 256 threads (4 waves, 2x2 of 64x64), 4x4 16x16x32 MFMAs per wave.
// LDS tiles [128][32] bf16 with XOR swizzle: slot q of row holds global chunk q^(row&3).
// EPI: 0 = bias -> bf16 ; 1 = bias + resid -> f32 ; 2 = bias + exact GELU -> bf16
template <int EPI>
__global__ __launch_bounds__(256) void gemm_bt(const unsigned short* __restrict__ A,
                                               const unsigned short* __restrict__ Bt,
                                               const float* __restrict__ bias,
                                               const float* __restrict__ resid,
                                               void* __restrict__ outp,
                                               int M, int N, int K) {
    __shared__ __align__(16) unsigned short sA[128 * 32];
    __shared__ __align__(16) unsigned short sB[128 * 32];
    const int t = threadIdx.x;
    const int lane = t & 63;
    const int w = t >> 6;
    const int wm = (w >> 1) * 64;
    const int wn = (w & 1) * 64;
    const int quad = lane >> 4;
    const int cl = lane & 15;
    const int mBase = blockIdx.y * 128;
    const int nBase = blockIdx.x * 128;
    const int r0 = t >> 2;  // 0..63
    const int q0 = t & 3;   // 16B chunk slot

    f32x4 acc[4][4] = {};

    for (int k0 = 0; k0 < K; k0 += 32) {
#pragma unroll
        for (int u = 0; u < 2; ++u) {
            const int row = r0 + u * 64;
            const int ca = q0 ^ (row & 3);
            *(int4*)(sA + row * 32 + q0 * 8) =
                *(const int4*)(A + (size_t)(mBase + row) * K + k0 + ca * 8);
            *(int4*)(sB + row * 32 + q0 * 8) =
                *(const int4*)(Bt + (size_t)(nBase + row) * K + k0 + ca * 8);
        }
        __syncthreads();
        bf16x8 af[4], bfr[4];
#pragma unroll
        for (int i = 0; i < 4; ++i) {
            const int ra = wm + i * 16 + cl;
            af[i] = *(const bf16x8*)(sA + ra * 32 + ((quad ^ (ra & 3)) * 8));
            const int rb = wn + i * 16 + cl;
            bfr[i] = *(const bf16x8*)(sB + rb * 32 + ((quad ^ (rb & 3)) * 8));
        }
#pragma unroll
        for (int i = 0; i < 4; ++i)
#pragma unroll
            for (int j = 0; j < 4; ++j)
                acc[i][j] =
                    __builtin_amdgcn_mfma_f32_16x16x32_bf16(af[i], bfr[j], acc[i][j], 0, 0, 0);
        __syncthreads();
    }

    // C/D layout (verified m89): col = lane&15, row = quad*4 + reg
#pragma unroll
    for (int i = 0; i < 4; ++i) {
        const int rowg = mBase + wm + i * 16 + quad * 4;
#pragma unroll
        for (int j = 0; j < 4; ++j) {
            const int colg = nBase + wn + j * 16 + cl;
            const float bv = bias[colg];
#pragma unroll
            for (int rr = 0; rr < 4; ++rr) {
                const float v = acc[i][j][rr] + bv;
                const size_t idx = (size_t)(rowg + rr) * N + colg;
                if constexpr (EPI == 0) {
                    ((unsigned short*)outp)[idx] = f2bf(v);
                } else if constexpr (EPI == 1) {
                    ((float*)outp)[idx] = v + resid[idx];
                } else {
                    const float g = 0.5f * v * (1.0f + erff(v * 0.70710678118654752f));
                    ((unsigned short*)outp)[idx] = f2bf(g);
                }
            }
        }
    }
}

// ---------------- flash attention, fp32 VALU ----------------
// block = 256 threads, one (b,h, 64-row q-tile). Thread t: r = t/4 (q row), t&3
// owns 16 key-cols for QK^T and 16 d-cols for PV. K-tiles of 64 keys, online softmax.
// LDS: Qs,Ks,Vs [64][68] f32; P reuses Ks (extra barrier after scores). 52.2 KB -> 3 blocks/CU.
__global__ __launch_bounds__(256) void attn_kernel(const unsigned short* __restrict__ qkv,
                                                   unsigned short* __restrict__ ctx) {
    constexpr int ST = 68;
    __shared__ __align__(16) float Qs[64 * ST];
    __shared__ __align__(16) float Ks[64 * ST];
    __shared__ __align__(16) float Vs[64 * ST];
    float* const Pl = Ks;
    const int bh = blockIdx.x;
    const int qt = blockIdx.y;
    const int b = bh >> 4;
    const int h = bh & 15;
    const int t = threadIdx.x;
    const int r = t >> 2;
    const int c16 = (t & 3) * 16;
    const int tok0 = b * 1024;

    {
        const unsigned short* qp = qkv + (size_t)(tok0 + qt * 64 + r) * 3072 + h * 64 + c16;
#pragma unroll
        for (int u = 0; u < 2; ++u) {
            u16x8 qv = *(const u16x8*)(qp + u * 8);
#pragma unroll
            for (int j = 0; j < 8; ++j) Qs[r * ST + c16 + u * 8 + j] = bf2f(qv[j]);
        }
    }
    float m = -3.0e38f, l = 0.0f;
    float O[16];
#pragma unroll
    for (int i = 0; i < 16; ++i) O[i] = 0.0f;

    for (int kt = 0; kt < 16; ++kt) {
        {
            const unsigned short* kp =
                qkv + (size_t)(tok0 + kt * 64 + r) * 3072 + 1024 + h * 64 + c16;
#pragma unroll
            for (int u = 0; u < 2; ++u) {
                u16x8 kv = *(const u16x8*)(kp + u * 8);
                u16x8 vv = *(const u16x8*)(kp + 1024 + u * 8);
#pragma unroll
                for (int j = 0; j < 8; ++j) {
                    Ks[r * ST + c16 + u * 8 + j] = bf2f(kv[j]);
                    Vs[r * ST + c16 + u * 8 + j] = bf2f(vv[j]);
                }
            }
        }
        __syncthreads();

        float s[16];
#pragma unroll
        for (int i = 0; i < 16; ++i) s[i] = 0.0f;
#pragma unroll 4
        for (int d0 = 0; d0 < 64; d0 += 4) {
            const float4 q4 = *(const float4*)&Qs[r * ST + d0];
#pragma unroll
            for (int i = 0; i < 16; ++i) {
                const float4 k4 = *(const float4*)&Ks[(c16 + i) * ST + d0];
                s[i] += q4.x * k4.x + q4.y * k4.y + q4.z * k4.z + q4.w * k4.w;
            }
        }
        __syncthreads();  // all reads of Ks done before Pl (aliased) is written

        float tmax = -3.0e38f;
#pragma unroll
        for (int i = 0; i < 16; ++i) {
            s[i] *= 0.125f;  // 1/sqrt(64)
            tmax = fmaxf(tmax, s[i]);
        }
        tmax = fmaxf(tmax, __shfl_xor(tmax, 1, 4));
        tmax = fmaxf(tmax, __shfl_xor(tmax, 2, 4));
        const float mnew = fmaxf(m, tmax);
        const float alpha = __expf(m - mnew);
        float psum = 0.0f;
#pragma unroll
        for (int i = 0; i < 16; ++i) {
            s[i] = __expf(s[i] - mnew);
            psum += s[i];
        }
        psum += __shfl_xor(psum, 1, 4);
        psum += __shfl_xor(psum, 2, 4);
        l = l * alpha + psum;
        m = mnew;
#pragma unroll
        for (int i = 0; i < 16; ++i) O[i] *= alpha;
#pragma unroll
        for (int i = 0; i < 16; ++i) Pl[r * ST + c16 + i] = s[i];
        __syncthreads();

#pragma unroll 2
        for (int k = 0; k < 64; ++k) {
            const float p = Pl[r * ST + k];
            const float4 v0 = *(const float4*)&Vs[k * ST + c16];
            const float4 v1 = *(const float4*)&Vs[k * ST + c16 + 4];
            const float4 v2 = *(const float4*)&Vs[k * ST + c16 + 8];
            const float4 v3 = *(const float4*)&Vs[k * ST + c16 + 12];
            O[0] += p * v0.x;  O[1] += p * v0.y;  O[2] += p * v0.z;  O[3] += p * v0.w;
            O[4] += p * v1.x;  O[5] += p * v1.y;  O[6] += p * v1.z;  O[7] += p * v1.w;
            O[8] += p * v2.x;  O[9] += p * v2.y;  O[10] += p * v2.z; O[11] += p * v2.w;
            O[12] += p * v3.x; O[13] += p * v3.y; O[14] += p * v3.z; O[15] += p * v3.w;
        }
        __syncthreads();  // PV reads done before next tile restages Ks/Vs
    }

    const float inv = 1.0f / l;
    unsigned short* op = ctx + (size_t)(tok0 + qt * 64 + r) * 1024 + h * 64 + c16;
#pragma unroll
    for (int u = 0; u < 2; ++u) {
        u16x8 o8;
#pragma unroll
        for (int j = 0; j < 8; ++j) o8[j] = f2bf(O[u * 8 + j] * inv);
        *(u16x8*)(op + u * 8) = o8;
    }
}

extern "C" void kernel_launch(void* const* d_in, const int* in_sizes, int n_in,
                              void* d_out, int out_size, void* d_ws, size_t ws_size,
                              hipStream_t stream) {
    const float* x    = (const float*)d_in[0];
    const float* wqkv = (const float*)d_in[1];
    const float* bqkv = (const float*)d_in[2];
    const float* wo   = (const float*)d_in[3];
    const float* bo   = (const float*)d_in[4];
    const float* w1   = (const float*)d_in[5];
    const float* b1   = (const float*)d_in[6];
    const float* w2   = (const float*)d_in[7];
    const float* b2   = (const float*)d_in[8];
    const float* n1w  = (const float*)d_in[9];
    const float* n1b  = (const float*)d_in[10];
    const float* n2w  = (const float*)d_in[11];
    const float* n2b  = (const float*)d_in[12];
    float* out = (float*)d_out;   // also serves as x1 (residual stream after attention)

    char* ws = (char*)d_ws;
    unsigned short* wqkv_b = (unsigned short*)(ws);
    unsigned short* wo_b   = (unsigned short*)(ws + 6291456);
    unsigned short* w1_b   = (unsigned short*)(ws + 8388608);
    unsigned short* w2_b   = (unsigned short*)(ws + 16777216);
    // region1 (32 MB): xn -> ctx -> xn2
    unsigned short* r1     = (unsigned short*)(ws + 25165824);
    // region2 (96 MB): qkv -> h chunks (64 MB)
    unsigned short* r2     = (unsigned short*)(ws + 58720256);

    unsigned short* xn_b  = r1;
    unsigned short* ctx_b = r1;
    unsigned short* xn2_b = r1;
    unsigned short* qkv_b = r2;
    unsigned short* h_b   = r2;

    // weights -> bf16
    cvt_kernel<<<3072, 256, 0, stream>>>(wqkv, wqkv_b, 786432);
    cvt_kernel<<<1024, 256, 0, stream>>>(wo, wo_b, 262144);
    cvt_kernel<<<4096, 256, 0, stream>>>(w1, w1_b, 1048576);
    cvt_kernel<<<4096, 256, 0, stream>>>(w2, w2_b, 1048576);

    // xn = LN1(x)
    ln_kernel<<<16384, 256, 0, stream>>>(x, n1w, n1b, xn_b);
    // qkv = xn @ Wqkv^T + b
    gemm_bt<0><<<dim3(24, 128), 256, 0, stream>>>(xn_b, wqkv_b, bqkv, nullptr, qkv_b,
                                                  16384, 3072, 1024);
    // ctx = attention(qkv)   (writes region1; xn dead)
    attn_kernel<<<dim3(256, 16), 256, 0, stream>>>(qkv_b, ctx_b);
    // d_out = x + ctx @ Wo^T + bo   (x1 lives in d_out; qkv dead after this consumer chain)
    gemm_bt<1><<<dim3(8, 128), 256, 0, stream>>>(ctx_b, wo_b, bo, x, out, 16384, 1024, 1024);
    // xn2 = LN2(d_out)   (writes region1; ctx dead)
    ln_kernel<<<16384, 256, 0, stream>>>(out, n2w, n2b, xn2_b);

    // FFN in 2 row-chunks of 8192 tokens; h chunk (64 MB bf16) reuses region2 (qkv dead)
    for (int c = 0; c < 2; ++c) {
        const size_t row0 = (size_t)c * 8192;
        // h = gelu(xn2 @ W1^T + b1)
        gemm_bt<2><<<dim3(32, 64), 256, 0, stream>>>(xn2_b + row0 * 1024, w1_b, b1, nullptr,
                                                     h_b, 8192, 4096, 1024);
        // d_out = d_out + h @ W2^T + b2   (in-place residual, same-thread read->write)
        gemm_bt<1><<<dim3(8, 64), 256, 0, stream>>>(h_b, w2_b, b2, out + row0 * 1024,
                                                    out + row0 * 1024, 8192, 1024, 4096);
    }
}

// Round 3
// 1067.260 us; speedup vs baseline: 3.0681x; 3.0681x over previous
//
#include <hip/hip_runtime.h>

// B=16,S=1024,E=1024,F=4096,H=16,D=64. N = B*S = 16384 tokens.
// Pipeline: LN1 -> QKV gemm(bf16 MFMA)+bias -> MFMA flash attn -> proj gemm+bias+resid -> d_out
//           -> LN2 -> [2 row-chunks] lin1 gemm+bias+GELU -> lin2 gemm+bias+resid(in-place d_out)
//
// Workspace plan (peak ~152 MB):
//   0          wqkv_b  bf16 3072x1024   (6 MB)
//   6291456    wo_b    bf16 1024x1024   (2 MB)
//   8388608    w1_b    bf16 4096x1024   (8 MB)
//   16777216   w2_b    bf16 1024x4096   (8 MB)
//   25165824   region1 (32 MB): xn_b -> ctx_b -> xn2_b
//   58720256   region2 (96 MB): qkv_b -> h chunk (64 MB, FFN in 2 row-chunks)
// x1 (fp32) lives in d_out; lin2 updates d_out in place (same-thread R->W).

typedef __attribute__((ext_vector_type(8))) short bf16x8;
typedef __attribute__((ext_vector_type(4))) float f32x4;
typedef __attribute__((ext_vector_type(8))) unsigned short u16x8;
typedef __attribute__((ext_vector_type(4))) unsigned short u16x4;

__device__ __forceinline__ float bf2f(unsigned short u) {
    return __uint_as_float(((unsigned int)u) << 16);
}
__device__ __forceinline__ unsigned short f2bf(float f) {
    unsigned int u = __float_as_uint(f);
    u += 0x7fffu + ((u >> 16) & 1u);   // RNE
    return (unsigned short)(u >> 16);
}

// ---------------- fp32 -> bf16 weight conversion ----------------
__global__ __launch_bounds__(256) void cvt_kernel(const float* __restrict__ in,
                                                  unsigned short* __restrict__ out, int n4) {
    int i = blockIdx.x * 256 + threadIdx.x;
    if (i >= n4) return;
    float4 v = ((const float4*)in)[i];
    u16x4 o;
    o[0] = f2bf(v.x); o[1] = f2bf(v.y); o[2] = f2bf(v.z); o[3] = f2bf(v.w);
    ((u16x4*)out)[i] = o;
}

// ---------------- LayerNorm (E=1024), fp32 in -> bf16 out ----------------
__global__ __launch_bounds__(256) void ln_kernel(const float* __restrict__ x,
                                                 const float* __restrict__ w,
                                                 const float* __restrict__ b,
                                                 unsigned short* __restrict__ out) {
    const int row = blockIdx.x;
    const int t = threadIdx.x;
    const float* xr = x + (size_t)row * 1024;
    float4 v = *(const float4*)(xr + t * 4);
    float s = v.x + v.y + v.z + v.w;
    float sq = v.x * v.x + v.y * v.y + v.z * v.z + v.w * v.w;
#pragma unroll
    for (int off = 32; off > 0; off >>= 1) {
        s += __shfl_xor(s, off);
        sq += __shfl_xor(sq, off);
    }
    __shared__ float rs_[4], rq_[4];
    if ((t & 63) == 0) { rs_[t >> 6] = s; rq_[t >> 6] = sq; }
    __syncthreads();
    s = rs_[0] + rs_[1] + rs_[2] + rs_[3];
    sq = rq_[0] + rq_[1] + rq_[2] + rq_[3];
    const float mu = s * (1.0f / 1024.0f);
    const float var = sq * (1.0f / 1024.0f) - mu * mu;
    const float rstd = rsqrtf(var + 1e-5f);
    const int c = t * 4;
    float4 wv = *(const float4*)(w + c);
    float4 bv = *(const float4*)(b + c);
    u16x4 o;
    o[0] = f2bf((v.x - mu) * rstd * wv.x + bv.x);
    o[1] = f2bf((v.y - mu) * rstd * wv.y + bv.y);
    o[2] = f2bf((v.z - mu) * rstd * wv.z + bv.z);
    o[3] = f2bf((v.w - mu) * rstd * wv.w + bv.w);
    *(u16x4*)(out + (size_t)row * 1024 + c) = o;
}

// ---------------- bf16 MFMA GEMM: C[M,N] = A[M,K] @ Bt[N,K]^T + epilogue ----------------
// 128x128 tile, BK=32, 256 threads (4 waves, 2x2 of 64x64), 4x4 16x16x32 MFMAs per wave.
// EPI: 0 = bias -> bf16 ; 1 = bias + resid -> f32 ; 2 = bias + exact GELU -> bf16
template <int EPI>
__global__ __launch_bounds__(256) void gemm_bt(const unsigned short* __restrict__ A,
                                               const unsigned short* __restrict__ Bt,
                                               const float* __restrict__ bias,
                                               const float* __restrict__ resid,
                                               void* __restrict__ outp,
                                               int M, int N, int K) {
    __shared__ __align__(16) unsigned short sA[128 * 32];
    __shared__ __align__(16) unsigned short sB[128 * 32];
    const int t = threadIdx.x;
    const int lane = t & 63;
    const int w = t >> 6;
    const int wm = (w >> 1) * 64;
    const int wn = (w & 1) * 64;
    const int quad = lane >> 4;
    const int cl = lane & 15;
    const int mBase = blockIdx.y * 128;
    const int nBase = blockIdx.x * 128;
    const int r0 = t >> 2;  // 0..63
    const int q0 = t & 3;   // 16B chunk slot

    f32x4 acc[4][4] = {};

    for (int k0 = 0; k0 < K; k0 += 32) {
#pragma unroll
        for (int u = 0; u < 2; ++u) {
            const int row = r0 + u * 64;
            const int ca = q0 ^ (row & 3);
            *(int4*)(sA + row * 32 + q0 * 8) =
                *(const int4*)(A + (size_t)(mBase + row) * K + k0 + ca * 8);
            *(int4*)(sB + row * 32 + q0 * 8) =
                *(const int4*)(Bt + (size_t)(nBase + row) * K + k0 + ca * 8);
        }
        __syncthreads();
        bf16x8 af[4], bfr[4];
#pragma unroll
        for (int i = 0; i < 4; ++i) {
            const int ra = wm + i * 16 + cl;
            af[i] = *(const bf16x8*)(sA + ra * 32 + ((quad ^ (ra & 3)) * 8));
            const int rb = wn + i * 16 + cl;
            bfr[i] = *(const bf16x8*)(sB + rb * 32 + ((quad ^ (rb & 3)) * 8));
        }
#pragma unroll
        for (int i = 0; i < 4; ++i)
#pragma unroll
            for (int j = 0; j < 4; ++j)
                acc[i][j] =
                    __builtin_amdgcn_mfma_f32_16x16x32_bf16(af[i], bfr[j], acc[i][j], 0, 0, 0);
        __syncthreads();
    }

    // C/D layout: col = lane&15, row = quad*4 + reg
#pragma unroll
    for (int i = 0; i < 4; ++i) {
        const int rowg = mBase + wm + i * 16 + quad * 4;
#pragma unroll
        for (int j = 0; j < 4; ++j) {
            const int colg = nBase + wn + j * 16 + cl;
            const float bv = bias[colg];
#pragma unroll
            for (int rr = 0; rr < 4; ++rr) {
                const float v = acc[i][j][rr] + bv;
                const size_t idx = (size_t)(rowg + rr) * N + colg;
                if constexpr (EPI == 0) {
                    ((unsigned short*)outp)[idx] = f2bf(v);
                } else if constexpr (EPI == 1) {
                    ((float*)outp)[idx] = v + resid[idx];
                } else {
                    const float g = 0.5f * v * (1.0f + erff(v * 0.70710678118654752f));
                    ((unsigned short*)outp)[idx] = f2bf(g);
                }
            }
        }
    }
}

// ---------------- MFMA flash attention ----------------
// Block = 256 threads (4 waves). blockIdx.x = b*16+h, blockIdx.y = q-tile (64 rows).
// Wave w owns q-rows qt*64 + w*16 .. +15. Per 64-key tile:
//   QK^T: A=Q frags (regs), B=K from LDS [key][72] -> S 16x64 in C-layout (4 f32x4)
//   online softmax in-register (scale 1/8 folded into exp fma; row state per quad)
//   P -> wave-private LDS rows [16][72] (C-layout write, A-layout b128 read)
//   PV: B=V^T stored as key-pair dwords [d][36], group-swizzled by (kp>>2)^(d>>3)
// LDS: Ks 9216 + Vt 9216 + Ps 9216 = 27.6 KB. 2 barriers/tile.
__global__ __launch_bounds__(256) void attn_mfma(const unsigned short* __restrict__ qkv,
                                                 unsigned short* __restrict__ ctx) {
    __shared__ __align__(16) unsigned short Ks[64 * 72];
    __shared__ __align__(16) unsigned int Vt[64 * 36];
    __shared__ __align__(16) unsigned short Ps[64 * 72];

    const int bh = blockIdx.x;
    const int qt = blockIdx.y;
    const int b = bh >> 4;
    const int h = bh & 15;
    const int t = threadIdx.x;
    const int w = t >> 6;
    const int lane = t & 63;
    const int quad = lane >> 4;
    const int cl = lane & 15;
    const size_t tok0 = (size_t)b * 1024;

    // Q fragments (A-layout): m = cl (wave q-row), k = quad*8 + ks*32
    bf16x8 aq[2];
    {
        const unsigned short* qp =
            qkv + (tok0 + qt * 64 + w * 16 + cl) * 3072 + h * 64 + quad * 8;
        aq[0] = *(const bf16x8*)(qp);
        aq[1] = *(const bf16x8*)(qp + 32);
    }

    // staging indices
    const int r0 = t >> 2;         // K row 0..63
    const int c16 = (t & 3) * 16;  // K col chunk
    const int kp = t >> 3;         // V key-pair 0..31
    const int dc = t & 7;          // V d-chunk (8 d's)

    f32x4 acc[4] = {};             // PV accum: C rows quad*4+rr (q), cols j*16+cl (d)
    float m_r[4], l_r[4];
#pragma unroll
    for (int rr = 0; rr < 4; ++rr) { m_r[rr] = -3.0e38f; l_r[rr] = 0.0f; }

    for (int kt = 0; kt < 16; ++kt) {
        // ---- stage K [key][d] and V^T [d][key-pair dword] ----
        {
            const unsigned short* kg =
                qkv + (tok0 + kt * 64 + r0) * 3072 + 1024 + h * 64 + c16;
            *(int4*)(Ks + r0 * 72 + c16) = *(const int4*)(kg);
            *(int4*)(Ks + r0 * 72 + c16 + 8) = *(const int4*)(kg + 8);

            const unsigned short* vg =
                qkv + (tok0 + kt * 64 + 2 * kp) * 3072 + 2048 + h * 64 + dc * 8;
            u16x8 v0 = *(const u16x8*)(vg);
            u16x8 v1 = *(const u16x8*)(vg + 3072);
            const int g = kp >> 2, wd = kp & 3;
#pragma unroll
            for (int j = 0; j < 8; ++j) {
                const int d = dc * 8 + j;
                Vt[d * 36 + (((g ^ (d >> 3)) << 2) | wd)] =
                    ((unsigned int)v1[j] << 16) | (unsigned int)v0[j];
            }
        }
        __syncthreads();

        // ---- QK^T ----
        f32x4 sc[4] = {};
#pragma unroll
        for (int i = 0; i < 4; ++i) {
            const int rb = i * 16 + cl;
#pragma unroll
            for (int ks = 0; ks < 2; ++ks) {
                bf16x8 bk = *(const bf16x8*)(Ks + rb * 72 + quad * 8 + ks * 32);
                sc[i] = __builtin_amdgcn_mfma_f32_16x16x32_bf16(aq[ks], bk, sc[i], 0, 0, 0);
            }
        }

        // ---- online softmax (rows quad*4+rr; reduce across 16 lanes of quad) ----
        float p[4][4];
#pragma unroll
        for (int rr = 0; rr < 4; ++rr) {
            float rmax = fmaxf(fmaxf(sc[0][rr], sc[1][rr]), fmaxf(sc[2][rr], sc[3][rr]));
#pragma unroll
            for (int off = 1; off < 16; off <<= 1) rmax = fmaxf(rmax, __shfl_xor(rmax, off, 16));
            const float mnew = fmaxf(m_r[rr], rmax * 0.125f);
            const float alpha = __expf(m_r[rr] - mnew);
            m_r[rr] = mnew;
            float psum = 0.0f;
#pragma unroll
            for (int j = 0; j < 4; ++j) {
                p[j][rr] = __expf(fmaf(sc[j][rr], 0.125f, -mnew));
                psum += p[j][rr];
            }
#pragma unroll
            for (int off = 1; off < 16; off <<= 1) psum += __shfl_xor(psum, off, 16);
            l_r[rr] = l_r[rr] * alpha + psum;
#pragma unroll
            for (int j = 0; j < 4; ++j) acc[j][rr] *= alpha;
        }

        // ---- P -> wave-private LDS (C-layout write), re-read in A-layout ----
#pragma unroll
        for (int rr = 0; rr < 4; ++rr)
#pragma unroll
            for (int j = 0; j < 4; ++j)
                Ps[(w * 16 + quad * 4 + rr) * 72 + j * 16 + cl] = f2bf(p[j][rr]);

        // ---- PV ----
#pragma unroll
        for (int ks = 0; ks < 2; ++ks) {
            bf16x8 ap = *(const bf16x8*)(Ps + (w * 16 + cl) * 72 + quad * 8 + ks * 32);
#pragma unroll
            for (int j = 0; j < 4; ++j) {
                const int d = j * 16 + cl;
                bf16x8 bv = *(const bf16x8*)(Vt + d * 36 + (((quad + 4 * ks) ^ (d >> 3)) << 2));
                acc[j] = __builtin_amdgcn_mfma_f32_16x16x32_bf16(ap, bv, acc[j], 0, 0, 0);
            }
        }
        __syncthreads();  // Ks/Vt reads done before next staging
    }

    // ---- epilogue: O = acc / l, bf16 store ----
    float inv[4];
#pragma unroll
    for (int rr = 0; rr < 4; ++rr) inv[rr] = 1.0f / l_r[rr];
#pragma unroll
    for (int rr = 0; rr < 4; ++rr) {
        const size_t tok = tok0 + qt * 64 + w * 16 + quad * 4 + rr;
#pragma unroll
        for (int j = 0; j < 4; ++j)
            ctx[tok * 1024 + h * 64 + j * 16 + cl] = f2bf(acc[j][rr] * inv[rr]);
    }
}

extern "C" void kernel_launch(void* const* d_in, const int* in_sizes, int n_in,
                              void* d_out, int out_size, void* d_ws, size_t ws_size,
                              hipStream_t stream) {
    const float* x    = (const float*)d_in[0];
    const float* wqkv = (const float*)d_in[1];
    const float* bqkv = (const float*)d_in[2];
    const float* wo   = (const float*)d_in[3];
    const float* bo   = (const float*)d_in[4];
    const float* w1   = (const float*)d_in[5];
    const float* b1   = (const float*)d_in[6];
    const float* w2   = (const float*)d_in[7];
    const float* b2   = (const float*)d_in[8];
    const float* n1w  = (const float*)d_in[9];
    const float* n1b  = (const float*)d_in[10];
    const float* n2w  = (const float*)d_in[11];
    const float* n2b  = (const float*)d_in[12];
    float* out = (float*)d_out;   // also serves as x1 (residual stream after attention)

    char* ws = (char*)d_ws;
    unsigned short* wqkv_b = (unsigned short*)(ws);
    unsigned short* wo_b   = (unsigned short*)(ws + 6291456);
    unsigned short* w1_b   = (unsigned short*)(ws + 8388608);
    unsigned short* w2_b   = (unsigned short*)(ws + 16777216);
    unsigned short* r1     = (unsigned short*)(ws + 25165824);  // xn -> ctx -> xn2
    unsigned short* r2     = (unsigned short*)(ws + 58720256);  // qkv -> h chunks

    unsigned short* xn_b  = r1;
    unsigned short* ctx_b = r1;
    unsigned short* xn2_b = r1;
    unsigned short* qkv_b = r2;
    unsigned short* h_b   = r2;

    cvt_kernel<<<3072, 256, 0, stream>>>(wqkv, wqkv_b, 786432);
    cvt_kernel<<<1024, 256, 0, stream>>>(wo, wo_b, 262144);
    cvt_kernel<<<4096, 256, 0, stream>>>(w1, w1_b, 1048576);
    cvt_kernel<<<4096, 256, 0, stream>>>(w2, w2_b, 1048576);

    ln_kernel<<<16384, 256, 0, stream>>>(x, n1w, n1b, xn_b);
    gemm_bt<0><<<dim3(24, 128), 256, 0, stream>>>(xn_b, wqkv_b, bqkv, nullptr, qkv_b,
                                                  16384, 3072, 1024);
    attn_mfma<<<dim3(256, 16), 256, 0, stream>>>(qkv_b, ctx_b);
    gemm_bt<1><<<dim3(8, 128), 256, 0, stream>>>(ctx_b, wo_b, bo, x, out, 16384, 1024, 1024);
    ln_kernel<<<16384, 256, 0, stream>>>(out, n2w, n2b, xn2_b);

    for (int c = 0; c < 2; ++c) {
        const size_t row0 = (size_t)c * 8192;
        gemm_bt<2><<<dim3(32, 64), 256, 0, stream>>>(xn2_b + row0 * 1024, w1_b, b1, nullptr,
                                                     h_b, 8192, 4096, 1024);
        gemm_bt<1><<<dim3(8, 64), 256, 0, stream>>>(h_b, w2_b, b2, out + row0 * 1024,
                                                    out + row0 * 1024, 8192, 1024, 4096);
    }
}